// Round 2
// baseline (1014.045 us; speedup 1.0000x reference)
//
#include <hip/hip_runtime.h>
#include <math.h>

// Problem constants
#define B_    2
#define S_    2048
#define DIM_  4096
#define NH_   32
#define NKV_  8
#define HD_   128
#define MROWS (B_ * S_)             // 4096
#define QDIM  (NH_ * HD_)           // 4096
#define KVDIM (NKV_ * HD_)           // 1024

typedef unsigned short ushort_t;
typedef __attribute__((ext_vector_type(8))) short bf16x8;   // 8 bf16 = 4 VGPRs
typedef __attribute__((ext_vector_type(4))) float f32x4;    // MFMA 16x16 accum

#define MFMA16(a, b, c) __builtin_amdgcn_mfma_f32_16x16x32_bf16(a, b, c, 0, 0, 0)

__device__ __forceinline__ float bf2f(ushort_t u) {
  return __uint_as_float(((unsigned int)u) << 16);
}
__device__ __forceinline__ ushort_t f2bf(float f) {
  unsigned int x = __float_as_uint(f);
  return (ushort_t)((x + 0x7fffu + ((x >> 16) & 1u)) >> 16);  // RNE
}
// Async global->LDS, 16B per lane. LDS dst is wave-uniform base; HW adds lane*16.
__device__ __forceinline__ void gload16(const void* g, void* l) {
  __builtin_amdgcn_global_load_lds(
      (const __attribute__((address_space(1))) void*)g,
      (__attribute__((address_space(3))) void*)l, 16, 0, 0);
}

// ---------------------------------------------------------------------------
// f32 -> bf16 convert, 8 elems/thread
// ---------------------------------------------------------------------------
__global__ void conv_f32_bf16(const float* __restrict__ in,
                              ushort_t* __restrict__ out) {
  int i = blockIdx.x * 256 + threadIdx.x;
  float4 a = ((const float4*)in)[i * 2 + 0];
  float4 b = ((const float4*)in)[i * 2 + 1];
  bf16x8 o;
  o[0] = (short)f2bf(a.x); o[1] = (short)f2bf(a.y);
  o[2] = (short)f2bf(a.z); o[3] = (short)f2bf(a.w);
  o[4] = (short)f2bf(b.x); o[5] = (short)f2bf(b.y);
  o[6] = (short)f2bf(b.z); o[7] = (short)f2bf(b.w);
  ((bf16x8*)out)[i] = o;
}

// ---------------------------------------------------------------------------
// bf16 MFMA GEMM: C[M,N] = A[M,K] @ W[N,K]^T (m97-class structure, unchanged)
// ---------------------------------------------------------------------------
template <int OUT_MODE>
__global__ __launch_bounds__(256, 2) void gemm_bf16(
    const ushort_t* __restrict__ A, const ushort_t* __restrict__ W,
    void* __restrict__ Cv, int M, int N, int K) {
  constexpr int BK = 32;
  __shared__ ushort_t As[128 * BK];   // [m][k] row stride 64B
  __shared__ ushort_t Ws[128 * BK];   // [n][k]
  const int tid = threadIdx.x, lane = tid & 63, w = tid >> 6;
  const int quad = lane >> 4, l16 = lane & 15;
  const int row0 = blockIdx.y * 128, col0 = blockIdx.x * 128;
  const int wm = (w & 1) * 64, wn = (w >> 1) * 64;

  f32x4 acc[4][4] = {};

  for (int k0 = 0; k0 < K; k0 += BK) {
    __syncthreads();
#pragma unroll
    for (int i = 0; i < 2; ++i) {
      int c = i * 256 + w * 64 + lane;          // 16B chunk id, 4 chunks/row
      int r = c >> 2, ko = (c & 3) * 8;
      gload16(A + (size_t)(row0 + r) * K + k0 + ko,
              (char*)As + (i * 256 + w * 64) * 16);
      gload16(W + (size_t)(col0 + r) * K + k0 + ko,
              (char*)Ws + (i * 256 + w * 64) * 16);
    }
    __syncthreads();

    bf16x8 af[4], bfr[4];
#pragma unroll
    for (int mt = 0; mt < 4; ++mt)
      af[mt] = *(const bf16x8*)((char*)As + (wm + mt * 16 + l16) * 64 + quad * 16);
#pragma unroll
    for (int nt = 0; nt < 4; ++nt)
      bfr[nt] = *(const bf16x8*)((char*)Ws + (wn + nt * 16 + l16) * 64 + quad * 16);
#pragma unroll
    for (int mt = 0; mt < 4; ++mt)
#pragma unroll
      for (int nt = 0; nt < 4; ++nt)
        acc[mt][nt] = MFMA16(af[mt], bfr[nt], acc[mt][nt]);
  }

#pragma unroll
  for (int mt = 0; mt < 4; ++mt)
#pragma unroll
    for (int nt = 0; nt < 4; ++nt)
#pragma unroll
      for (int r = 0; r < 4; ++r) {
        int row = row0 + wm + mt * 16 + quad * 4 + r;
        int col = col0 + wn + nt * 16 + l16;
        float v = acc[mt][nt][r];
        if (OUT_MODE == 0)
          ((ushort_t*)Cv)[(size_t)row * N + col] = f2bf(v);
        else if (OUT_MODE == 1)
          ((float*)Cv)[(size_t)row * N + col] = v;
        else
          ((ushort_t*)Cv)[(size_t)col * M + row] = f2bf(v);  // C^T
      }
}

// ---------------------------------------------------------------------------
// RoPE in place on bf16 q and k (unchanged)
// ---------------------------------------------------------------------------
__global__ void rope_bf16(ushort_t* __restrict__ q, ushort_t* __restrict__ k,
                          const float* __restrict__ cs,
                          const float* __restrict__ sn) {
  int idx = blockIdx.x * 256 + threadIdx.x;
  int jg = (idx & 15) * 4;
  int t = idx >> 4;
  int hh = t % (NH_ + NKV_);
  int bs = t / (NH_ + NKV_);
  int s = bs & (S_ - 1);
  float4 c4 = *(const float4*)(cs + s * 64 + jg);
  float4 s4 = *(const float4*)(sn + s * 64 + jg);
  ushort_t* p = (hh < NH_)
      ? q + (size_t)bs * QDIM + hh * HD_ + 2 * jg
      : k + (size_t)bs * KVDIM + (hh - NH_) * HD_ + 2 * jg;
  bf16x8 v = *(const bf16x8*)p;
  float cc[4] = {c4.x, c4.y, c4.z, c4.w};
  float ss[4] = {s4.x, s4.y, s4.z, s4.w};
  bf16x8 o;
#pragma unroll
  for (int u = 0; u < 4; ++u) {
    float xr = bf2f((ushort_t)v[2 * u]);
    float xi = bf2f((ushort_t)v[2 * u + 1]);
    o[2 * u]     = (short)f2bf(xr * cc[u] - xi * ss[u]);
    o[2 * u + 1] = (short)f2bf(xr * ss[u] + xi * cc[u]);
  }
  *(bf16x8*)p = o;
}

// ---------------------------------------------------------------------------
// MFMA flash attention v3: double-buffered K/V with prefetch-ahead.
// Block = 4 waves; BQ=64 (16 q-rows/wave), BKV=64.
// LDS: Kbuf[2] 64x256B swizzled (c^=r&15), Vbuf[2] (V^T) 128x128B swizzled
// (c^=r&7), per-wave P 16 rows x 144B.  One barrier per kv-iteration; tile
// kt+1's global_load_lds issued BEFORE computing tile kt, so the vmcnt drain
// at the barrier lands after ~1k cycles of compute (T3 2-phase minimum).
// LPT: qt = 31 - blockIdx.x launches long causal blocks first.
// ---------------------------------------------------------------------------
__global__ __launch_bounds__(256, 2) void attn_mfma(
    const ushort_t* __restrict__ qb, const ushort_t* __restrict__ kb,
    const ushort_t* __restrict__ vt, ushort_t* __restrict__ ob) {
  __shared__ __align__(16) char smem[2 * 16384 + 2 * 16384 + 4 * 2304];
  const int tid = threadIdx.x, lane = tid & 63, w = tid >> 6;
  const int quad = lane >> 4, l16 = lane & 15;
  char* psw = smem + 65536 + w * 2304;   // per-wave P: 16 rows x 144B
  const int qt = (S_ / 64 - 1) - blockIdx.x;   // LPT order
  const int h = blockIdx.y, b = blockIdx.z;
  const int kvh = h >> 2;
  const int q0 = qt * 64;
  const float C = 0.12756113f;        // (1/sqrt(128)) * log2(e)

  // ---- prologue: stage Q -> Kbuf1, K0 -> Kbuf0, V0 -> Vbuf0 ----
#pragma unroll
  for (int i = 0; i < 4; ++i) {
    int r0 = w * 16 + i * 4;
    int r = r0 + (lane >> 4);
    int c = (lane & 15) ^ (r & 15);
    gload16(qb + (size_t)(b * S_ + q0 + r) * QDIM + h * HD_ + c * 8,
            smem + 16384 + r0 * 256);
    gload16(kb + (size_t)(b * S_ + r) * KVDIM + kvh * HD_ + c * 8,
            smem + r0 * 256);
    int vr0 = w * 32 + i * 8;
    int vr = vr0 + (lane >> 3);
    int vc = (lane & 7) ^ (vr & 7);
    gload16(vt + (size_t)(kvh * HD_ + vr) * MROWS + b * S_ + vc * 8,
            smem + 32768 + vr0 * 128);
  }
  __syncthreads();

  // Q fragments out of Kbuf1 (each wave reads only rows it staged itself)
  bf16x8 qf[4];
#pragma unroll
  for (int t = 0; t < 4; ++t)
    qf[t] = *(const bf16x8*)(smem + 16384 + (w * 16 + l16) * 256 +
                             (((t * 4 + quad) ^ l16) * 16));
  // qf must land before the kt=0 prefetch overwrites Kbuf1 (same-wave rows)
  asm volatile("s_waitcnt lgkmcnt(0)" ::: "memory");

  float m_[4], l_[4];
  f32x4 o_[8] = {};
#pragma unroll
  for (int r = 0; r < 4; ++r) { m_[r] = -1e30f; l_[r] = 0.f; }

  for (int kt = 0; kt <= qt; ++kt) {
    char* Kc = smem + (kt & 1) * 16384;
    char* Vc = smem + 32768 + (kt & 1) * 16384;

    // ---- prefetch tile kt+1 into the other buffer (drains at the barrier) --
    if (kt < qt) {
      char* Kn = smem + ((kt + 1) & 1) * 16384;
      char* Vn = smem + 32768 + ((kt + 1) & 1) * 16384;
#pragma unroll
      for (int i = 0; i < 4; ++i) {
        int r0 = w * 16 + i * 4;
        int r = r0 + (lane >> 4);
        int c = (lane & 15) ^ (r & 15);
        gload16(kb + (size_t)(b * S_ + (kt + 1) * 64 + r) * KVDIM + kvh * HD_ + c * 8,
                Kn + r0 * 256);
        int vr0 = w * 32 + i * 8;
        int vr = vr0 + (lane >> 3);
        int vc = (lane & 7) ^ (vr & 7);
        gload16(vt + (size_t)(kvh * HD_ + vr) * MROWS + b * S_ + (kt + 1) * 64 + vc * 8,
                Vn + vr0 * 128);
      }
    }

    // ---- S = Q K^T : 4 kv tiles of 16 (skip fully-masked tiles on diag) ----
    const int ntmax = (kt == qt) ? w : 3;
    f32x4 s[4];
    __builtin_amdgcn_s_setprio(1);
#pragma unroll
    for (int nt = 0; nt < 4; ++nt) {
      if (nt <= ntmax) {
        f32x4 a = {0.f, 0.f, 0.f, 0.f};
#pragma unroll
        for (int t = 0; t < 4; ++t) {
          bf16x8 kf = *(const bf16x8*)(Kc + (nt * 16 + l16) * 256 +
                                       (((t * 4 + quad) ^ l16) * 16));
          a = MFMA16(qf[t], kf, a);
        }
        s[nt] = a;
      } else {
        s[nt] = (f32x4){-INFINITY, -INFINITY, -INFINITY, -INFINITY};
      }
    }
    __builtin_amdgcn_s_setprio(0);

    // ---- online softmax (exp2 domain; rows = quad*4+r, cols = l16) ----
    float p[4][4], al[4];
#pragma unroll
    for (int r = 0; r < 4; ++r) {
      float v[4];
#pragma unroll
      for (int nt = 0; nt < 4; ++nt) {
        float vv = s[nt][r] * C;
        if (kt == qt && nt == w && l16 > quad * 4 + r) vv = -INFINITY;
        v[nt] = vv;
      }
      float mx = fmaxf(fmaxf(v[0], v[1]), fmaxf(v[2], v[3]));
#pragma unroll
      for (int d = 1; d < 16; d <<= 1) mx = fmaxf(mx, __shfl_xor(mx, d, 64));
      float mnew = fmaxf(m_[r], mx);
      float a0 = __builtin_amdgcn_exp2f(m_[r] - mnew);
      float sum = 0.f;
#pragma unroll
      for (int nt = 0; nt < 4; ++nt) {
        p[nt][r] = __builtin_amdgcn_exp2f(v[nt] - mnew);
        sum += p[nt][r];
      }
#pragma unroll
      for (int d = 1; d < 16; d <<= 1) sum += __shfl_xor(sum, d, 64);
      l_[r] = l_[r] * a0 + sum;
      m_[r] = mnew;
      al[r] = a0;
    }

    // ---- P -> per-wave LDS first (lgkm wait overlaps the O-rescale) ----
#pragma unroll
    for (int r = 0; r < 4; ++r)
#pragma unroll
      for (int nt = 0; nt < 4; ++nt)
        ((ushort_t*)psw)[(quad * 4 + r) * 72 + nt * 16 + l16] = f2bf(p[nt][r]);

#pragma unroll
    for (int dt = 0; dt < 8; ++dt)
#pragma unroll
      for (int r = 0; r < 4; ++r) o_[dt][r] *= al[r];

    asm volatile("s_waitcnt lgkmcnt(0)" ::: "memory");
    bf16x8 pf[2];
#pragma unroll
    for (int kc = 0; kc < 2; ++kc)
      pf[kc] = *(const bf16x8*)(psw + l16 * 144 + kc * 64 + quad * 16);

    // ---- O += P V : 8 d-tiles x 2 k-chunks ----
    __builtin_amdgcn_s_setprio(1);
#pragma unroll
    for (int dt = 0; dt < 8; ++dt) {
#pragma unroll
      for (int kc = 0; kc < 2; ++kc) {
        bf16x8 vf = *(const bf16x8*)(Vc + (dt * 16 + l16) * 128 +
                                     (((kc * 4 + quad) ^ (l16 & 7)) * 16));
        o_[dt] = MFMA16(pf[kc], vf, o_[dt]);
      }
    }
    __builtin_amdgcn_s_setprio(0);

    __syncthreads();   // reads of buf[cur] done + prefetch of buf[cur^1] drained
  }

  // ---- epilogue: normalize, store bf16 (b,s,h,d) ----
#pragma unroll
  for (int r = 0; r < 4; ++r) {
    float linv = 1.0f / l_[r];
    size_t base = (size_t)(b * S_ + q0 + w * 16 + quad * 4 + r) * QDIM + h * HD_;
#pragma unroll
    for (int dt = 0; dt < 8; ++dt)
      ob[base + dt * 16 + l16] = f2bf(o_[dt][r] * linv);
  }
}

// ---------------------------------------------------------------------------
// Launch. Workspace layout (MiB offsets), 160 MiB total:
//   0: xb(32, reused for wob) | 32: wqb(32) | 64: wkb(8) | 72: wvb(8)
//  80: qbuf(32) | 112: kbuf(8) | 120: vtb(8) | 128: attnb(32)
// ---------------------------------------------------------------------------
extern "C" void kernel_launch(void* const* d_in, const int* in_sizes, int n_in,
                              void* d_out, int out_size, void* d_ws, size_t ws_size,
                              hipStream_t stream) {
  const float* x  = (const float*)d_in[0];
  const float* wq = (const float*)d_in[1];
  const float* wk = (const float*)d_in[2];
  const float* wv = (const float*)d_in[3];
  const float* wo = (const float*)d_in[4];
  const float* fc = (const float*)d_in[5];
  const float* fs = (const float*)d_in[6];
  float* out = (float*)d_out;

  char* ws = (char*)d_ws;
  ushort_t* xb    = (ushort_t*)(ws);
  ushort_t* wqb   = (ushort_t*)(ws + (32ull << 20));
  ushort_t* wkb   = (ushort_t*)(ws + (64ull << 20));
  ushort_t* wvb   = (ushort_t*)(ws + (72ull << 20));
  ushort_t* qbuf  = (ushort_t*)(ws + (80ull << 20));
  ushort_t* kbuf  = (ushort_t*)(ws + (112ull << 20));
  ushort_t* vtb   = (ushort_t*)(ws + (120ull << 20));
  ushort_t* attnb = (ushort_t*)(ws + (128ull << 20));
  ushort_t* wob   = xb;  // x dead after projections

  dim3 blk(256);

  conv_f32_bf16<<<(MROWS * DIM_) / 2048, blk, 0, stream>>>(x, xb);
  conv_f32_bf16<<<(QDIM * DIM_) / 2048, blk, 0, stream>>>(wq, wqb);
  conv_f32_bf16<<<(KVDIM * DIM_) / 2048, blk, 0, stream>>>(wk, wkb);
  conv_f32_bf16<<<(KVDIM * DIM_) / 2048, blk, 0, stream>>>(wv, wvb);

  gemm_bf16<0><<<dim3(QDIM / 128, MROWS / 128), blk, 0, stream>>>(xb, wqb, qbuf, MROWS, QDIM, DIM_);
  gemm_bf16<0><<<dim3(KVDIM / 128, MROWS / 128), blk, 0, stream>>>(xb, wkb, kbuf, MROWS, KVDIM, DIM_);
  gemm_bf16<2><<<dim3(KVDIM / 128, MROWS / 128), blk, 0, stream>>>(xb, wvb, vtb, MROWS, KVDIM, DIM_);

  rope_bf16<<<(MROWS * (NH_ + NKV_) * 16) / 256, blk, 0, stream>>>(qbuf, kbuf, fc, fs);

  attn_mfma<<<dim3(S_ / 64, NH_, B_), blk, 0, stream>>>(qbuf, kbuf, vtb, attnb);

  conv_f32_bf16<<<(QDIM * DIM_) / 2048, blk, 0, stream>>>(wo, wob);
  gemm_bf16<1><<<dim3(QDIM / 128, MROWS / 128), blk, 0, stream>>>(attnb, wob, out, MROWS, QDIM, DIM_);
}

// Round 3
// 853.392 us; speedup vs baseline: 1.1883x; 1.1883x over previous
//
#include <hip/hip_runtime.h>
#include <math.h>

// Problem constants
#define B_    2
#define S_    2048
#define DIM_  4096
#define NH_   32
#define NKV_  8
#define HD_   128
#define MROWS (B_ * S_)             // 4096
#define QDIM  (NH_ * HD_)           // 4096
#define KVDIM (NKV_ * HD_)          // 1024

typedef unsigned short ushort_t;
typedef __attribute__((ext_vector_type(8))) short bf16x8;   // 8 bf16 = 4 VGPRs
typedef __attribute__((ext_vector_type(4))) float f32x4;    // MFMA 16x16 accum

#define MFMA16(a, b, c) __builtin_amdgcn_mfma_f32_16x16x32_bf16(a, b, c, 0, 0, 0)

__device__ __forceinline__ float bf2f(ushort_t u) {
  return __uint_as_float(((unsigned int)u) << 16);
}
__device__ __forceinline__ ushort_t f2bf(float f) {
  unsigned int x = __float_as_uint(f);
  return (ushort_t)((x + 0x7fffu + ((x >> 16) & 1u)) >> 16);  // RNE
}
// Async global->LDS, 16B per lane. LDS dst is wave-uniform base; HW adds lane*16.
__device__ __forceinline__ void gload16(const void* g, void* l) {
  __builtin_amdgcn_global_load_lds(
      (const __attribute__((address_space(1))) void*)g,
      (__attribute__((address_space(3))) void*)l, 16, 0, 0);
}

// ---------------------------------------------------------------------------
// f32 -> bf16 convert, 8 elems/thread
// ---------------------------------------------------------------------------
__global__ void conv_f32_bf16(const float* __restrict__ in,
                              ushort_t* __restrict__ out) {
  int i = blockIdx.x * 256 + threadIdx.x;
  float4 a = ((const float4*)in)[i * 2 + 0];
  float4 b = ((const float4*)in)[i * 2 + 1];
  bf16x8 o;
  o[0] = (short)f2bf(a.x); o[1] = (short)f2bf(a.y);
  o[2] = (short)f2bf(a.z); o[3] = (short)f2bf(a.w);
  o[4] = (short)f2bf(b.x); o[5] = (short)f2bf(b.y);
  o[6] = (short)f2bf(b.z); o[7] = (short)f2bf(b.w);
  ((bf16x8*)out)[i] = o;
}

// ---------------------------------------------------------------------------
// bf16 MFMA GEMM: C[M,N] = A[M,K] @ W[N,K]^T (m97-class structure, unchanged)
// ---------------------------------------------------------------------------
template <int OUT_MODE>
__global__ __launch_bounds__(256, 2) void gemm_bf16(
    const ushort_t* __restrict__ A, const ushort_t* __restrict__ W,
    void* __restrict__ Cv, int M, int N, int K) {
  constexpr int BK = 32;
  __shared__ ushort_t As[128 * BK];   // [m][k] row stride 64B
  __shared__ ushort_t Ws[128 * BK];   // [n][k]
  const int tid = threadIdx.x, lane = tid & 63, w = tid >> 6;
  const int quad = lane >> 4, l16 = lane & 15;
  const int row0 = blockIdx.y * 128, col0 = blockIdx.x * 128;
  const int wm = (w & 1) * 64, wn = (w >> 1) * 64;

  f32x4 acc[4][4] = {};

  for (int k0 = 0; k0 < K; k0 += BK) {
    __syncthreads();
#pragma unroll
    for (int i = 0; i < 2; ++i) {
      int c = i * 256 + w * 64 + lane;          // 16B chunk id, 4 chunks/row
      int r = c >> 2, ko = (c & 3) * 8;
      gload16(A + (size_t)(row0 + r) * K + k0 + ko,
              (char*)As + (i * 256 + w * 64) * 16);
      gload16(W + (size_t)(col0 + r) * K + k0 + ko,
              (char*)Ws + (i * 256 + w * 64) * 16);
    }
    __syncthreads();

    bf16x8 af[4], bfr[4];
#pragma unroll
    for (int mt = 0; mt < 4; ++mt)
      af[mt] = *(const bf16x8*)((char*)As + (wm + mt * 16 + l16) * 64 + quad * 16);
#pragma unroll
    for (int nt = 0; nt < 4; ++nt)
      bfr[nt] = *(const bf16x8*)((char*)Ws + (wn + nt * 16 + l16) * 64 + quad * 16);
#pragma unroll
    for (int mt = 0; mt < 4; ++mt)
#pragma unroll
      for (int nt = 0; nt < 4; ++nt)
        acc[mt][nt] = MFMA16(af[mt], bfr[nt], acc[mt][nt]);
  }

#pragma unroll
  for (int mt = 0; mt < 4; ++mt)
#pragma unroll
    for (int nt = 0; nt < 4; ++nt)
#pragma unroll
      for (int r = 0; r < 4; ++r) {
        int row = row0 + wm + mt * 16 + quad * 4 + r;
        int col = col0 + wn + nt * 16 + l16;
        float v = acc[mt][nt][r];
        if (OUT_MODE == 0)
          ((ushort_t*)Cv)[(size_t)row * N + col] = f2bf(v);
        else if (OUT_MODE == 1)
          ((float*)Cv)[(size_t)row * N + col] = v;
        else
          ((ushort_t*)Cv)[(size_t)col * M + row] = f2bf(v);  // C^T
      }
}

// ---------------------------------------------------------------------------
// RoPE in place on bf16 q and k (unchanged)
// ---------------------------------------------------------------------------
__global__ void rope_bf16(ushort_t* __restrict__ q, ushort_t* __restrict__ k,
                          const float* __restrict__ cs,
                          const float* __restrict__ sn) {
  int idx = blockIdx.x * 256 + threadIdx.x;
  int jg = (idx & 15) * 4;
  int t = idx >> 4;
  int hh = t % (NH_ + NKV_);
  int bs = t / (NH_ + NKV_);
  int s = bs & (S_ - 1);
  float4 c4 = *(const float4*)(cs + s * 64 + jg);
  float4 s4 = *(const float4*)(sn + s * 64 + jg);
  ushort_t* p = (hh < NH_)
      ? q + (size_t)bs * QDIM + hh * HD_ + 2 * jg
      : k + (size_t)bs * KVDIM + (hh - NH_) * HD_ + 2 * jg;
  bf16x8 v = *(const bf16x8*)p;
  float cc[4] = {c4.x, c4.y, c4.z, c4.w};
  float ss[4] = {s4.x, s4.y, s4.z, s4.w};
  bf16x8 o;
#pragma unroll
  for (int u = 0; u < 4; ++u) {
    float xr = bf2f((ushort_t)v[2 * u]);
    float xi = bf2f((ushort_t)v[2 * u + 1]);
    o[2 * u]     = (short)f2bf(xr * cc[u] - xi * ss[u]);
    o[2 * u + 1] = (short)f2bf(xr * ss[u] + xi * cc[u]);
  }
  *(bf16x8*)p = o;
}

// ---------------------------------------------------------------------------
// MFMA flash attention v4: causal work PAIRING for uniform block duration.
// Each block processes q-tiles qtA = 31-x and qtB = x; combined kv-iteration
// count = (qtA+1)+(qtB+1) = 33 for every block -> perfect makespan packing
// (1024 uniform blocks over 512 resident slots = exactly 2 rounds).
// Inner structure unchanged from v3: 4 waves, BQ=64, BKV=64, double-buffered
// K/V with prefetch-ahead, one barrier per kv-iteration, XOR-swizzled LDS.
// ---------------------------------------------------------------------------
__global__ __launch_bounds__(256, 2) void attn_mfma(
    const ushort_t* __restrict__ qb, const ushort_t* __restrict__ kb,
    const ushort_t* __restrict__ vt, ushort_t* __restrict__ ob) {
  __shared__ __align__(16) char smem[2 * 16384 + 2 * 16384 + 4 * 2304];
  const int tid = threadIdx.x, lane = tid & 63, w = tid >> 6;
  const int quad = lane >> 4, l16 = lane & 15;
  char* psw = smem + 65536 + w * 2304;   // per-wave P: 16 rows x 144B
  const int h = blockIdx.y, b = blockIdx.z;
  const int kvh = h >> 2;
  const float C = 0.12756113f;        // (1/sqrt(128)) * log2(e)

  for (int half = 0; half < 2; ++half) {
    const int qt = (half == 0) ? (S_ / 64 - 1) - blockIdx.x : blockIdx.x;
    const int q0 = qt * 64;

    // ---- prologue: stage Q -> Kbuf1, K0 -> Kbuf0, V0 -> Vbuf0 ----
    // (tile B staging is safe: prior tile's last in-loop barrier drained all
    //  LDS reads; epilogue touches only registers + global)
#pragma unroll
    for (int i = 0; i < 4; ++i) {
      int r0 = w * 16 + i * 4;
      int r = r0 + (lane >> 4);
      int c = (lane & 15) ^ (r & 15);
      gload16(qb + (size_t)(b * S_ + q0 + r) * QDIM + h * HD_ + c * 8,
              smem + 16384 + r0 * 256);
      gload16(kb + (size_t)(b * S_ + r) * KVDIM + kvh * HD_ + c * 8,
              smem + r0 * 256);
      int vr0 = w * 32 + i * 8;
      int vr = vr0 + (lane >> 3);
      int vc = (lane & 7) ^ (vr & 7);
      gload16(vt + (size_t)(kvh * HD_ + vr) * MROWS + b * S_ + vc * 8,
              smem + 32768 + vr0 * 128);
    }
    __syncthreads();

    // Q fragments out of Kbuf1 (each wave reads only rows it staged itself)
    bf16x8 qf[4];
#pragma unroll
    for (int t = 0; t < 4; ++t)
      qf[t] = *(const bf16x8*)(smem + 16384 + (w * 16 + l16) * 256 +
                               (((t * 4 + quad) ^ l16) * 16));
    // qf must land before the kt=0 prefetch overwrites Kbuf1 (same-wave rows)
    asm volatile("s_waitcnt lgkmcnt(0)" ::: "memory");

    float m_[4], l_[4];
    f32x4 o_[8] = {};
#pragma unroll
    for (int r = 0; r < 4; ++r) { m_[r] = -1e30f; l_[r] = 0.f; }

    for (int kt = 0; kt <= qt; ++kt) {
      char* Kc = smem + (kt & 1) * 16384;
      char* Vc = smem + 32768 + (kt & 1) * 16384;

      // ---- prefetch tile kt+1 into the other buffer ----
      if (kt < qt) {
        char* Kn = smem + ((kt + 1) & 1) * 16384;
        char* Vn = smem + 32768 + ((kt + 1) & 1) * 16384;
#pragma unroll
        for (int i = 0; i < 4; ++i) {
          int r0 = w * 16 + i * 4;
          int r = r0 + (lane >> 4);
          int c = (lane & 15) ^ (r & 15);
          gload16(kb + (size_t)(b * S_ + (kt + 1) * 64 + r) * KVDIM + kvh * HD_ + c * 8,
                  Kn + r0 * 256);
          int vr0 = w * 32 + i * 8;
          int vr = vr0 + (lane >> 3);
          int vc = (lane & 7) ^ (vr & 7);
          gload16(vt + (size_t)(kvh * HD_ + vr) * MROWS + b * S_ + (kt + 1) * 64 + vc * 8,
                  Vn + vr0 * 128);
        }
      }

      // ---- S = Q K^T : 4 kv tiles of 16 (skip fully-masked tiles on diag) --
      const int ntmax = (kt == qt) ? w : 3;
      f32x4 s[4];
      __builtin_amdgcn_s_setprio(1);
#pragma unroll
      for (int nt = 0; nt < 4; ++nt) {
        if (nt <= ntmax) {
          f32x4 a = {0.f, 0.f, 0.f, 0.f};
#pragma unroll
          for (int t = 0; t < 4; ++t) {
            bf16x8 kf = *(const bf16x8*)(Kc + (nt * 16 + l16) * 256 +
                                         (((t * 4 + quad) ^ l16) * 16));
            a = MFMA16(qf[t], kf, a);
          }
          s[nt] = a;
        } else {
          s[nt] = (f32x4){-INFINITY, -INFINITY, -INFINITY, -INFINITY};
        }
      }
      __builtin_amdgcn_s_setprio(0);

      // ---- online softmax (exp2 domain; rows = quad*4+r, cols = l16) ----
      float p[4][4], al[4];
#pragma unroll
      for (int r = 0; r < 4; ++r) {
        float v[4];
#pragma unroll
        for (int nt = 0; nt < 4; ++nt) {
          float vv = s[nt][r] * C;
          if (kt == qt && nt == w && l16 > quad * 4 + r) vv = -INFINITY;
          v[nt] = vv;
        }
        float mx = fmaxf(fmaxf(v[0], v[1]), fmaxf(v[2], v[3]));
#pragma unroll
        for (int d = 1; d < 16; d <<= 1) mx = fmaxf(mx, __shfl_xor(mx, d, 64));
        float mnew = fmaxf(m_[r], mx);
        float a0 = __builtin_amdgcn_exp2f(m_[r] - mnew);
        float sum = 0.f;
#pragma unroll
        for (int nt = 0; nt < 4; ++nt) {
          p[nt][r] = __builtin_amdgcn_exp2f(v[nt] - mnew);
          sum += p[nt][r];
        }
#pragma unroll
        for (int d = 1; d < 16; d <<= 1) sum += __shfl_xor(sum, d, 64);
        l_[r] = l_[r] * a0 + sum;
        m_[r] = mnew;
        al[r] = a0;
      }

      // ---- P -> per-wave LDS first (lgkm wait overlaps the O-rescale) ----
#pragma unroll
      for (int r = 0; r < 4; ++r)
#pragma unroll
        for (int nt = 0; nt < 4; ++nt)
          ((ushort_t*)psw)[(quad * 4 + r) * 72 + nt * 16 + l16] = f2bf(p[nt][r]);

#pragma unroll
      for (int dt = 0; dt < 8; ++dt)
#pragma unroll
        for (int r = 0; r < 4; ++r) o_[dt][r] *= al[r];

      asm volatile("s_waitcnt lgkmcnt(0)" ::: "memory");
      bf16x8 pf[2];
#pragma unroll
      for (int kc = 0; kc < 2; ++kc)
        pf[kc] = *(const bf16x8*)(psw + l16 * 144 + kc * 64 + quad * 16);

      // ---- O += P V : 8 d-tiles x 2 k-chunks ----
      __builtin_amdgcn_s_setprio(1);
#pragma unroll
      for (int dt = 0; dt < 8; ++dt) {
#pragma unroll
        for (int kc = 0; kc < 2; ++kc) {
          bf16x8 vf = *(const bf16x8*)(Vc + (dt * 16 + l16) * 128 +
                                       (((kc * 4 + quad) ^ (l16 & 7)) * 16));
          o_[dt] = MFMA16(pf[kc], vf, o_[dt]);
        }
      }
      __builtin_amdgcn_s_setprio(0);

      __syncthreads();   // reads of buf[cur] done + prefetch of buf[cur^1] drained
    }

    // ---- epilogue: normalize, store bf16 (b,s,h,d) ----
#pragma unroll
    for (int r = 0; r < 4; ++r) {
      float linv = 1.0f / l_[r];
      size_t base = (size_t)(b * S_ + q0 + w * 16 + quad * 4 + r) * QDIM + h * HD_;
#pragma unroll
      for (int dt = 0; dt < 8; ++dt)
        ob[base + dt * 16 + l16] = f2bf(o_[dt][r] * linv);
    }
  }
}

// ---------------------------------------------------------------------------
// Launch. Workspace layout (MiB offsets), 160 MiB total:
//   0: xb(32, reused for wob) | 32: wqb(32) | 64: wkb(8) | 72: wvb(8)
//  80: qbuf(32) | 112: kbuf(8) | 120: vtb(8) | 128: attnb(32)
// ---------------------------------------------------------------------------
extern "C" void kernel_launch(void* const* d_in, const int* in_sizes, int n_in,
                              void* d_out, int out_size, void* d_ws, size_t ws_size,
                              hipStream_t stream) {
  const float* x  = (const float*)d_in[0];
  const float* wq = (const float*)d_in[1];
  const float* wk = (const float*)d_in[2];
  const float* wv = (const float*)d_in[3];
  const float* wo = (const float*)d_in[4];
  const float* fc = (const float*)d_in[5];
  const float* fs = (const float*)d_in[6];
  float* out = (float*)d_out;

  char* ws = (char*)d_ws;
  ushort_t* xb    = (ushort_t*)(ws);
  ushort_t* wqb   = (ushort_t*)(ws + (32ull << 20));
  ushort_t* wkb   = (ushort_t*)(ws + (64ull << 20));
  ushort_t* wvb   = (ushort_t*)(ws + (72ull << 20));
  ushort_t* qbuf  = (ushort_t*)(ws + (80ull << 20));
  ushort_t* kbuf  = (ushort_t*)(ws + (112ull << 20));
  ushort_t* vtb   = (ushort_t*)(ws + (120ull << 20));
  ushort_t* attnb = (ushort_t*)(ws + (128ull << 20));
  ushort_t* wob   = xb;  // x dead after projections

  dim3 blk(256);

  conv_f32_bf16<<<(MROWS * DIM_) / 2048, blk, 0, stream>>>(x, xb);
  conv_f32_bf16<<<(QDIM * DIM_) / 2048, blk, 0, stream>>>(wq, wqb);
  conv_f32_bf16<<<(KVDIM * DIM_) / 2048, blk, 0, stream>>>(wk, wkb);
  conv_f32_bf16<<<(KVDIM * DIM_) / 2048, blk, 0, stream>>>(wv, wvb);

  gemm_bf16<0><<<dim3(QDIM / 128, MROWS / 128), blk, 0, stream>>>(xb, wqb, qbuf, MROWS, QDIM, DIM_);
  gemm_bf16<0><<<dim3(KVDIM / 128, MROWS / 128), blk, 0, stream>>>(xb, wkb, kbuf, MROWS, KVDIM, DIM_);
  gemm_bf16<2><<<dim3(KVDIM / 128, MROWS / 128), blk, 0, stream>>>(xb, wvb, vtb, MROWS, KVDIM, DIM_);

  rope_bf16<<<(MROWS * (NH_ + NKV_) * 16) / 256, blk, 0, stream>>>(qbuf, kbuf, fc, fs);

  // Paired causal tiles: grid.x = 16, each block does qt = 31-x and qt = x.
  attn_mfma<<<dim3(S_ / 128, NH_, B_), blk, 0, stream>>>(qbuf, kbuf, vtb, attnb);

  conv_f32_bf16<<<(QDIM * DIM_) / 2048, blk, 0, stream>>>(wo, wob);
  gemm_bf16<1><<<dim3(QDIM / 128, MROWS / 128), blk, 0, stream>>>(attnb, wob, out, MROWS, QDIM, DIM_);
}

// Round 4
// 787.271 us; speedup vs baseline: 1.2881x; 1.0840x over previous
//
#include <hip/hip_runtime.h>
#include <math.h>

// Problem constants
#define B_    2
#define S_    2048
#define DIM_  4096
#define NH_   32
#define NKV_  8
#define HD_   128
#define MROWS (B_ * S_)             // 4096
#define QDIM  (NH_ * HD_)           // 4096
#define KVDIM (NKV_ * HD_)          // 1024

typedef unsigned short ushort_t;
typedef __attribute__((ext_vector_type(8))) short bf16x8;   // 8 bf16 = 4 VGPRs
typedef __attribute__((ext_vector_type(4))) float f32x4;    // MFMA 16x16 accum

#define MFMA16(a, b, c) __builtin_amdgcn_mfma_f32_16x16x32_bf16(a, b, c, 0, 0, 0)

__device__ __forceinline__ float bf2f(ushort_t u) {
  return __uint_as_float(((unsigned int)u) << 16);
}
__device__ __forceinline__ ushort_t f2bf(float f) {
  unsigned int x = __float_as_uint(f);
  return (ushort_t)((x + 0x7fffu + ((x >> 16) & 1u)) >> 16);  // RNE
}
// Async global->LDS, 16B per lane. LDS dst is wave-uniform base; HW adds lane*16.
__device__ __forceinline__ void gload16(const void* g, void* l) {
  __builtin_amdgcn_global_load_lds(
      (const __attribute__((address_space(1))) void*)g,
      (__attribute__((address_space(3))) void*)l, 16, 0, 0);
}

// ---------------------------------------------------------------------------
// f32 -> bf16 convert, 8 elems/thread
// ---------------------------------------------------------------------------
__global__ void conv_f32_bf16(const float* __restrict__ in,
                              ushort_t* __restrict__ out) {
  int i = blockIdx.x * 256 + threadIdx.x;
  float4 a = ((const float4*)in)[i * 2 + 0];
  float4 b = ((const float4*)in)[i * 2 + 1];
  bf16x8 o;
  o[0] = (short)f2bf(a.x); o[1] = (short)f2bf(a.y);
  o[2] = (short)f2bf(a.z); o[3] = (short)f2bf(a.w);
  o[4] = (short)f2bf(b.x); o[5] = (short)f2bf(b.y);
  o[6] = (short)f2bf(b.z); o[7] = (short)f2bf(b.w);
  ((bf16x8*)out)[i] = o;
}

// ---------------------------------------------------------------------------
// bf16 MFMA GEMM, 128x128 tile (m97 structure) — kept for K/V projections
// (N=1024: 256 blocks at 128^2 beats 64 blocks at 256^2).
// ---------------------------------------------------------------------------
template <int OUT_MODE>
__global__ __launch_bounds__(256, 2) void gemm_bf16(
    const ushort_t* __restrict__ A, const ushort_t* __restrict__ W,
    void* __restrict__ Cv, int M, int N, int K) {
  constexpr int BK = 32;
  __shared__ ushort_t As[128 * BK];   // [m][k] row stride 64B
  __shared__ ushort_t Ws[128 * BK];   // [n][k]
  const int tid = threadIdx.x, lane = tid & 63, w = tid >> 6;
  const int quad = lane >> 4, l16 = lane & 15;
  const int row0 = blockIdx.y * 128, col0 = blockIdx.x * 128;
  const int wm = (w & 1) * 64, wn = (w >> 1) * 64;

  f32x4 acc[4][4] = {};

  for (int k0 = 0; k0 < K; k0 += BK) {
    __syncthreads();
#pragma unroll
    for (int i = 0; i < 2; ++i) {
      int c = i * 256 + w * 64 + lane;          // 16B chunk id, 4 chunks/row
      int r = c >> 2, ko = (c & 3) * 8;
      gload16(A + (size_t)(row0 + r) * K + k0 + ko,
              (char*)As + (i * 256 + w * 64) * 16);
      gload16(W + (size_t)(col0 + r) * K + k0 + ko,
              (char*)Ws + (i * 256 + w * 64) * 16);
    }
    __syncthreads();

    bf16x8 af[4], bfr[4];
#pragma unroll
    for (int mt = 0; mt < 4; ++mt)
      af[mt] = *(const bf16x8*)((char*)As + (wm + mt * 16 + l16) * 64 + quad * 16);
#pragma unroll
    for (int nt = 0; nt < 4; ++nt)
      bfr[nt] = *(const bf16x8*)((char*)Ws + (wn + nt * 16 + l16) * 64 + quad * 16);
#pragma unroll
    for (int mt = 0; mt < 4; ++mt)
#pragma unroll
      for (int nt = 0; nt < 4; ++nt)
        acc[mt][nt] = MFMA16(af[mt], bfr[nt], acc[mt][nt]);
  }

#pragma unroll
  for (int mt = 0; mt < 4; ++mt)
#pragma unroll
    for (int nt = 0; nt < 4; ++nt)
#pragma unroll
      for (int r = 0; r < 4; ++r) {
        int row = row0 + wm + mt * 16 + quad * 4 + r;
        int col = col0 + wn + nt * 16 + l16;
        float v = acc[mt][nt][r];
        if (OUT_MODE == 0)
          ((ushort_t*)Cv)[(size_t)row * N + col] = f2bf(v);
        else if (OUT_MODE == 1)
          ((float*)Cv)[(size_t)row * N + col] = v;
        else
          ((ushort_t*)Cv)[(size_t)col * M + row] = f2bf(v);  // C^T
      }
}

// ---------------------------------------------------------------------------
// 256x256-tile 8-phase GEMM (T2+T3/T4+T5 template, plain HIP).
// C[M,N] = A[M,K] @ W[N,K]^T. 512 threads = 8 waves (2M x 4N), per-wave
// output 128x64 (acc[8][4]). BK=64, LDS 128 KiB double-buffered:
//   buf b: A at b*32768 (256 rows x 128B), B at 65536 + b*32768.
// Swizzle: 16B chunk index cc ^= (row & 7)  — realized as linear
// global_load_lds dest + inverse-swizzled GLOBAL source (rule 21), swizzled
// ds_read_b128 on the fragment reads -> 2-way (free) instead of 16-way.
// Schedule per K-tile: 4 phases x {ds_read frags; [stage next tile ph0/ph1];
// raw s_barrier; lgkmcnt(0); sched_barrier; 16 MFMA (setprio 1); s_barrier}.
// Single vmcnt(0) at end of phase 3 with >=2 phases of slack — prefetched
// loads stay in flight across barriers (raw s_barrier emits no drain).
// ---------------------------------------------------------------------------
__device__ __forceinline__ void stage_half(const ushort_t* __restrict__ src,
                                           int rowBase, int k0, char* ldsHalf,
                                           int wid, int lane, int K) {
#pragma unroll
  for (int j = 0; j < 2; ++j) {
    int ct = wid * 64 + j * 512 + lane;     // chunk 0..1023 of 16B
    int r = ct >> 3, c = ct & 7;
    gload16(src + (size_t)(rowBase + r) * K + k0 + ((c ^ (r & 7)) << 3),
            ldsHalf + (wid * 64 + j * 512) * 16);
  }
}

__device__ __forceinline__ bf16x8 readfrag(const char* base, int row, int cc) {
  return *(const bf16x8*)(base + row * 128 + ((cc ^ (row & 7)) << 4));
}

template <int OUT_MODE>
__global__ __launch_bounds__(512, 2) void gemm256(
    const ushort_t* __restrict__ A, const ushort_t* __restrict__ W,
    void* __restrict__ Cv, int M, int N, int K) {
  __shared__ __align__(16) char lds[131072];
  const int tid = threadIdx.x, lane = tid & 63, wid = tid >> 6;
  const int quad = lane >> 4, l16 = lane & 15;
  const int wr = wid >> 2, wc = wid & 3;
  const int row0 = blockIdx.y * 256, col0 = blockIdx.x * 256;
  const int KT = K >> 6;

  f32x4 acc[8][4] = {};

  // ---- prologue: stage tile 0 into buf0, drain, align ----
  stage_half(A, row0,       0, lds,                 wid, lane, K);
  stage_half(A, row0 + 128, 0, lds + 16384,         wid, lane, K);
  stage_half(W, col0,       0, lds + 65536,         wid, lane, K);
  stage_half(W, col0 + 128, 0, lds + 65536 + 16384, wid, lane, K);
  asm volatile("s_waitcnt vmcnt(0)" ::: "memory");
  __builtin_amdgcn_s_barrier();

  for (int u = 0; u < KT; ++u) {
    char* bA = lds + (u & 1) * 32768;
    char* bB = lds + 65536 + (u & 1) * 32768;
    char* nA = lds + ((u + 1) & 1) * 32768;
    char* nB = lds + 65536 + ((u + 1) & 1) * 32768;
    const bool st = (u + 1 < KT);
    const int kn = (u + 1) << 6;

    bf16x8 bfrag[4][2];
#pragma unroll
    for (int ph = 0; ph < 4; ++ph) {
      // fragment ds_reads for this phase (current tile, swizzled)
      bf16x8 afr[2][2];
#pragma unroll
      for (int mi = 0; mi < 2; ++mi)
#pragma unroll
        for (int kc = 0; kc < 2; ++kc)
          afr[mi][kc] =
              readfrag(bA, wr * 128 + (ph * 2 + mi) * 16 + l16, kc * 4 + quad);
      if (ph == 0) {
#pragma unroll
        for (int nt = 0; nt < 4; ++nt)
#pragma unroll
          for (int kc = 0; kc < 2; ++kc)
            bfrag[nt][kc] = readfrag(bB, wc * 64 + nt * 16 + l16, kc * 4 + quad);
        if (st) {   // stage next tile's A halves into the other buffer
          stage_half(A, row0,       kn, nA,         wid, lane, K);
          stage_half(A, row0 + 128, kn, nA + 16384, wid, lane, K);
        }
      }
      if (ph == 1 && st) {  // next tile's B halves
        stage_half(W, col0,       kn, nB,         wid, lane, K);
        stage_half(W, col0 + 128, kn, nB + 16384, wid, lane, K);
      }

      __builtin_amdgcn_s_barrier();
      asm volatile("s_waitcnt lgkmcnt(0)" ::: "memory");
      __builtin_amdgcn_sched_barrier(0);   // rule 18: pin MFMA after the wait
      __builtin_amdgcn_s_setprio(1);
#pragma unroll
      for (int mi = 0; mi < 2; ++mi)
#pragma unroll
        for (int nt = 0; nt < 4; ++nt)
#pragma unroll
          for (int kc = 0; kc < 2; ++kc)
            acc[ph * 2 + mi][nt] =
                MFMA16(afr[mi][kc], bfrag[nt][kc], acc[ph * 2 + mi][nt]);
      __builtin_amdgcn_s_setprio(0);
      if (ph == 3)  // next tile fully landed before its phase-0 ds_reads
        asm volatile("s_waitcnt vmcnt(0)" ::: "memory");
      __builtin_amdgcn_s_barrier();
    }
  }

  // ---- epilogue ----
#pragma unroll
  for (int mt = 0; mt < 8; ++mt)
#pragma unroll
    for (int nt = 0; nt < 4; ++nt)
#pragma unroll
      for (int r = 0; r < 4; ++r) {
        int row = row0 + wr * 128 + mt * 16 + quad * 4 + r;
        int col = col0 + wc * 64 + nt * 16 + l16;
        float v = acc[mt][nt][r];
        if (OUT_MODE == 0)
          ((ushort_t*)Cv)[(size_t)row * N + col] = f2bf(v);
        else
          ((float*)Cv)[(size_t)row * N + col] = v;
      }
}

// ---------------------------------------------------------------------------
// RoPE in place on bf16 q and k (unchanged)
// ---------------------------------------------------------------------------
__global__ void rope_bf16(ushort_t* __restrict__ q, ushort_t* __restrict__ k,
                          const float* __restrict__ cs,
                          const float* __restrict__ sn) {
  int idx = blockIdx.x * 256 + threadIdx.x;
  int jg = (idx & 15) * 4;
  int t = idx >> 4;
  int hh = t % (NH_ + NKV_);
  int bs = t / (NH_ + NKV_);
  int s = bs & (S_ - 1);
  float4 c4 = *(const float4*)(cs + s * 64 + jg);
  float4 s4 = *(const float4*)(sn + s * 64 + jg);
  ushort_t* p = (hh < NH_)
      ? q + (size_t)bs * QDIM + hh * HD_ + 2 * jg
      : k + (size_t)bs * KVDIM + (hh - NH_) * HD_ + 2 * jg;
  bf16x8 v = *(const bf16x8*)p;
  float cc[4] = {c4.x, c4.y, c4.z, c4.w};
  float ss[4] = {s4.x, s4.y, s4.z, s4.w};
  bf16x8 o;
#pragma unroll
  for (int u = 0; u < 4; ++u) {
    float xr = bf2f((ushort_t)v[2 * u]);
    float xi = bf2f((ushort_t)v[2 * u + 1]);
    o[2 * u]     = (short)f2bf(xr * cc[u] - xi * ss[u]);
    o[2 * u + 1] = (short)f2bf(xr * ss[u] + xi * cc[u]);
  }
  *(bf16x8*)p = o;
}

// ---------------------------------------------------------------------------
// MFMA flash attention v4 (unchanged from round 3 — matched prediction).
// Causal work pairing: q-tiles qtA = 31-x and qtB = x per block; uniform 33
// kv-iterations per block -> near-perfect makespan packing.
// ---------------------------------------------------------------------------
__global__ __launch_bounds__(256, 2) void attn_mfma(
    const ushort_t* __restrict__ qb, const ushort_t* __restrict__ kb,
    const ushort_t* __restrict__ vt, ushort_t* __restrict__ ob) {
  __shared__ __align__(16) char smem[2 * 16384 + 2 * 16384 + 4 * 2304];
  const int tid = threadIdx.x, lane = tid & 63, w = tid >> 6;
  const int quad = lane >> 4, l16 = lane & 15;
  char* psw = smem + 65536 + w * 2304;   // per-wave P: 16 rows x 144B
  const int h = blockIdx.y, b = blockIdx.z;
  const int kvh = h >> 2;
  const float C = 0.12756113f;        // (1/sqrt(128)) * log2(e)

  for (int half = 0; half < 2; ++half) {
    const int qt = (half == 0) ? (S_ / 64 - 1) - blockIdx.x : blockIdx.x;
    const int q0 = qt * 64;

    // ---- prologue: stage Q -> Kbuf1, K0 -> Kbuf0, V0 -> Vbuf0 ----
#pragma unroll
    for (int i = 0; i < 4; ++i) {
      int r0 = w * 16 + i * 4;
      int r = r0 + (lane >> 4);
      int c = (lane & 15) ^ (r & 15);
      gload16(qb + (size_t)(b * S_ + q0 + r) * QDIM + h * HD_ + c * 8,
              smem + 16384 + r0 * 256);
      gload16(kb + (size_t)(b * S_ + r) * KVDIM + kvh * HD_ + c * 8,
              smem + r0 * 256);
      int vr0 = w * 32 + i * 8;
      int vr = vr0 + (lane >> 3);
      int vc = (lane & 7) ^ (vr & 7);
      gload16(vt + (size_t)(kvh * HD_ + vr) * MROWS + b * S_ + vc * 8,
              smem + 32768 + vr0 * 128);
    }
    __syncthreads();

    // Q fragments out of Kbuf1 (each wave reads only rows it staged itself)
    bf16x8 qf[4];
#pragma unroll
    for (int t = 0; t < 4; ++t)
      qf[t] = *(const bf16x8*)(smem + 16384 + (w * 16 + l16) * 256 +
                               (((t * 4 + quad) ^ l16) * 16));
    // qf must land before the kt=0 prefetch overwrites Kbuf1 (same-wave rows)
    asm volatile("s_waitcnt lgkmcnt(0)" ::: "memory");

    float m_[4], l_[4];
    f32x4 o_[8] = {};
#pragma unroll
    for (int r = 0; r < 4; ++r) { m_[r] = -1e30f; l_[r] = 0.f; }

    for (int kt = 0; kt <= qt; ++kt) {
      char* Kc = smem + (kt & 1) * 16384;
      char* Vc = smem + 32768 + (kt & 1) * 16384;

      // ---- prefetch tile kt+1 into the other buffer ----
      if (kt < qt) {
        char* Kn = smem + ((kt + 1) & 1) * 16384;
        char* Vn = smem + 32768 + ((kt + 1) & 1) * 16384;
#pragma unroll
        for (int i = 0; i < 4; ++i) {
          int r0 = w * 16 + i * 4;
          int r = r0 + (lane >> 4);
          int c = (lane & 15) ^ (r & 15);
          gload16(kb + (size_t)(b * S_ + (kt + 1) * 64 + r) * KVDIM + kvh * HD_ + c * 8,
                  Kn + r0 * 256);
          int vr0 = w * 32 + i * 8;
          int vr = vr0 + (lane >> 3);
          int vc = (lane & 7) ^ (vr & 7);
          gload16(vt + (size_t)(kvh * HD_ + vr) * MROWS + b * S_ + (kt + 1) * 64 + vc * 8,
                  Vn + vr0 * 128);
        }
      }

      // ---- S = Q K^T : 4 kv tiles of 16 (skip fully-masked tiles on diag) --
      const int ntmax = (kt == qt) ? w : 3;
      f32x4 s[4];
      __builtin_amdgcn_s_setprio(1);
#pragma unroll
      for (int nt = 0; nt < 4; ++nt) {
        if (nt <= ntmax) {
          f32x4 a = {0.f, 0.f, 0.f, 0.f};
#pragma unroll
          for (int t = 0; t < 4; ++t) {
            bf16x8 kf = *(const bf16x8*)(Kc + (nt * 16 + l16) * 256 +
                                         (((t * 4 + quad) ^ l16) * 16));
            a = MFMA16(qf[t], kf, a);
          }
          s[nt] = a;
        } else {
          s[nt] = (f32x4){-INFINITY, -INFINITY, -INFINITY, -INFINITY};
        }
      }
      __builtin_amdgcn_s_setprio(0);

      // ---- online softmax (exp2 domain; rows = quad*4+r, cols = l16) ----
      float p[4][4], al[4];
#pragma unroll
      for (int r = 0; r < 4; ++r) {
        float v[4];
#pragma unroll
        for (int nt = 0; nt < 4; ++nt) {
          float vv = s[nt][r] * C;
          if (kt == qt && nt == w && l16 > quad * 4 + r) vv = -INFINITY;
          v[nt] = vv;
        }
        float mx = fmaxf(fmaxf(v[0], v[1]), fmaxf(v[2], v[3]));
#pragma unroll
        for (int d = 1; d < 16; d <<= 1) mx = fmaxf(mx, __shfl_xor(mx, d, 64));
        float mnew = fmaxf(m_[r], mx);
        float a0 = __builtin_amdgcn_exp2f(m_[r] - mnew);
        float sum = 0.f;
#pragma unroll
        for (int nt = 0; nt < 4; ++nt) {
          p[nt][r] = __builtin_amdgcn_exp2f(v[nt] - mnew);
          sum += p[nt][r];
        }
#pragma unroll
        for (int d = 1; d < 16; d <<= 1) sum += __shfl_xor(sum, d, 64);
        l_[r] = l_[r] * a0 + sum;
        m_[r] = mnew;
        al[r] = a0;
      }

      // ---- P -> per-wave LDS first (lgkm wait overlaps the O-rescale) ----
#pragma unroll
      for (int r = 0; r < 4; ++r)
#pragma unroll
        for (int nt = 0; nt < 4; ++nt)
          ((ushort_t*)psw)[(quad * 4 + r) * 72 + nt * 16 + l16] = f2bf(p[nt][r]);

#pragma unroll
      for (int dt = 0; dt < 8; ++dt)
#pragma unroll
        for (int r = 0; r < 4; ++r) o_[dt][r] *= al[r];

      asm volatile("s_waitcnt lgkmcnt(0)" ::: "memory");
      bf16x8 pf[2];
#pragma unroll
      for (int kc = 0; kc < 2; ++kc)
        pf[kc] = *(const bf16x8*)(psw + l16 * 144 + kc * 64 + quad * 16);

      // ---- O += P V : 8 d-tiles x 2 k-chunks ----
      __builtin_amdgcn_s_setprio(1);
#pragma unroll
      for (int dt = 0; dt < 8; ++dt) {
#pragma unroll
        for (int kc = 0; kc < 2; ++kc) {
          bf16x8 vf = *(const bf16x8*)(Vc + (dt * 16 + l16) * 128 +
                                       (((kc * 4 + quad) ^ (l16 & 7)) * 16));
          o_[dt] = MFMA16(pf[kc], vf, o_[dt]);
        }
      }
      __builtin_amdgcn_s_setprio(0);

      __syncthreads();   // reads of buf[cur] done + prefetch of buf[cur^1] drained
    }

    // ---- epilogue: normalize, store bf16 (b,s,h,d) ----
#pragma unroll
    for (int r = 0; r < 4; ++r) {
      float linv = 1.0f / l_[r];
      size_t base = (size_t)(b * S_ + q0 + w * 16 + quad * 4 + r) * QDIM + h * HD_;
#pragma unroll
      for (int dt = 0; dt < 8; ++dt)
        ob[base + dt * 16 + l16] = f2bf(o_[dt][r] * linv);
    }
  }
}

// ---------------------------------------------------------------------------
// Launch. Workspace layout (MiB offsets), 160 MiB total:
//   0: xb(32, reused for wob) | 32: wqb(32) | 64: wkb(8) | 72: wvb(8)
//  80: qbuf(32) | 112: kbuf(8) | 120: vtb(8) | 128: attnb(32)
// ---------------------------------------------------------------------------
extern "C" void kernel_launch(void* const* d_in, const int* in_sizes, int n_in,
                              void* d_out, int out_size, void* d_ws, size_t ws_size,
                              hipStream_t stream) {
  const float* x  = (const float*)d_in[0];
  const float* wq = (const float*)d_in[1];
  const float* wk = (const float*)d_in[2];
  const float* wv = (const float*)d_in[3];
  const float* wo = (const float*)d_in[4];
  const float* fc = (const float*)d_in[5];
  const float* fs = (const float*)d_in[6];
  float* out = (float*)d_out;

  char* ws = (char*)d_ws;
  ushort_t* xb    = (ushort_t*)(ws);
  ushort_t* wqb   = (ushort_t*)(ws + (32ull << 20));
  ushort_t* wkb   = (ushort_t*)(ws + (64ull << 20));
  ushort_t* wvb   = (ushort_t*)(ws + (72ull << 20));
  ushort_t* qbuf  = (ushort_t*)(ws + (80ull << 20));
  ushort_t* kbuf  = (ushort_t*)(ws + (112ull << 20));
  ushort_t* vtb   = (ushort_t*)(ws + (120ull << 20));
  ushort_t* attnb = (ushort_t*)(ws + (128ull << 20));
  ushort_t* wob   = xb;  // x dead after projections

  dim3 blk(256);
  dim3 blk512(512);

  conv_f32_bf16<<<(MROWS * DIM_) / 2048, blk, 0, stream>>>(x, xb);
  conv_f32_bf16<<<(QDIM * DIM_) / 2048, blk, 0, stream>>>(wq, wqb);
  conv_f32_bf16<<<(KVDIM * DIM_) / 2048, blk, 0, stream>>>(wk, wkb);
  conv_f32_bf16<<<(KVDIM * DIM_) / 2048, blk, 0, stream>>>(wv, wvb);

  // Q projection: 256^2 8-phase kernel (16x16 blocks = 256 CUs, 1 block/CU)
  gemm256<0><<<dim3(QDIM / 256, MROWS / 256), blk512, 0, stream>>>(xb, wqb, qbuf, MROWS, QDIM, DIM_);
  gemm_bf16<0><<<dim3(KVDIM / 128, MROWS / 128), blk, 0, stream>>>(xb, wkb, kbuf, MROWS, KVDIM, DIM_);
  gemm_bf16<2><<<dim3(KVDIM / 128, MROWS / 128), blk, 0, stream>>>(xb, wvb, vtb, MROWS, KVDIM, DIM_);

  rope_bf16<<<(MROWS * (NH_ + NKV_) * 16) / 256, blk, 0, stream>>>(qbuf, kbuf, fc, fs);

  // Paired causal tiles: grid.x = 16, each block does qt = 31-x and qt = x.
  attn_mfma<<<dim3(S_ / 128, NH_, B_), blk, 0, stream>>>(qbuf, kbuf, vtb, attnb);

  conv_f32_bf16<<<(QDIM * DIM_) / 2048, blk, 0, stream>>>(wo, wob);
  // Output projection: 256^2 8-phase kernel, f32 out
  gemm256<1><<<dim3(QDIM / 256, MROWS / 256), blk512, 0, stream>>>(attnb, wob, out, MROWS, QDIM, DIM_);
}

// Round 5
// 765.147 us; speedup vs baseline: 1.3253x; 1.0289x over previous
//
#include <hip/hip_runtime.h>
#include <math.h>

// Problem constants
#define B_    2
#define S_    2048
#define DIM_  4096
#define NH_   32
#define NKV_  8
#define HD_   128
#define MROWS (B_ * S_)             // 4096
#define QDIM  (NH_ * HD_)           // 4096
#define KVDIM (NKV_ * HD_)          // 1024

typedef unsigned short ushort_t;
typedef __attribute__((ext_vector_type(8))) short bf16x8;   // 8 bf16 = 4 VGPRs
typedef __attribute__((ext_vector_type(4))) float f32x4;    // MFMA 16x16 accum

#define MFMA16(a, b, c) __builtin_amdgcn_mfma_f32_16x16x32_bf16(a, b, c, 0, 0, 0)

__device__ __forceinline__ float bf2f(ushort_t u) {
  return __uint_as_float(((unsigned int)u) << 16);
}
__device__ __forceinline__ ushort_t f2bf(float f) {
  unsigned int x = __float_as_uint(f);
  return (ushort_t)((x + 0x7fffu + ((x >> 16) & 1u)) >> 16);  // RNE
}
// Async global->LDS, 16B per lane. LDS dst is wave-uniform base; HW adds lane*16.
__device__ __forceinline__ void gload16(const void* g, void* l) {
  __builtin_amdgcn_global_load_lds(
      (const __attribute__((address_space(1))) void*)g,
      (__attribute__((address_space(3))) void*)l, 16, 0, 0);
}

// DPP lane permute on f32 (VALU pipe, replaces LDS-pipe __shfl_xor).
// CTRL: 0xB1 = quad_perm xor1, 0x4E = quad_perm xor2,
//       0x141 = ROW_HALF_MIRROR (combines 4-groups within 8),
//       0x140 = ROW_MIRROR (combines 8-groups within 16-lane row).
template <int CTRL>
__device__ __forceinline__ float dpp_f(float x) {
  return __int_as_float(__builtin_amdgcn_update_dpp(
      0, __float_as_int(x), CTRL, 0xF, 0xF, true));
}
__device__ __forceinline__ float dpp_max16(float x) {
  x = fmaxf(x, dpp_f<0xB1>(x));
  x = fmaxf(x, dpp_f<0x4E>(x));
  x = fmaxf(x, dpp_f<0x141>(x));
  x = fmaxf(x, dpp_f<0x140>(x));
  return x;
}
__device__ __forceinline__ float dpp_sum16(float x) {
  x += dpp_f<0xB1>(x);
  x += dpp_f<0x4E>(x);
  x += dpp_f<0x141>(x);
  x += dpp_f<0x140>(x);
  return x;
}

// ---------------------------------------------------------------------------
// f32 -> bf16 convert, 8 elems/thread
// ---------------------------------------------------------------------------
__global__ void conv_f32_bf16(const float* __restrict__ in,
                              ushort_t* __restrict__ out) {
  int i = blockIdx.x * 256 + threadIdx.x;
  float4 a = ((const float4*)in)[i * 2 + 0];
  float4 b = ((const float4*)in)[i * 2 + 1];
  bf16x8 o;
  o[0] = (short)f2bf(a.x); o[1] = (short)f2bf(a.y);
  o[2] = (short)f2bf(a.z); o[3] = (short)f2bf(a.w);
  o[4] = (short)f2bf(b.x); o[5] = (short)f2bf(b.y);
  o[6] = (short)f2bf(b.z); o[7] = (short)f2bf(b.w);
  ((bf16x8*)out)[i] = o;
}

// ---------------------------------------------------------------------------
// bf16 MFMA GEMM, 128x128 tile (m97 structure) — kept for K/V projections
// ---------------------------------------------------------------------------
template <int OUT_MODE>
__global__ __launch_bounds__(256, 2) void gemm_bf16(
    const ushort_t* __restrict__ A, const ushort_t* __restrict__ W,
    void* __restrict__ Cv, int M, int N, int K) {
  constexpr int BK = 32;
  __shared__ ushort_t As[128 * BK];   // [m][k] row stride 64B
  __shared__ ushort_t Ws[128 * BK];   // [n][k]
  const int tid = threadIdx.x, lane = tid & 63, w = tid >> 6;
  const int quad = lane >> 4, l16 = lane & 15;
  const int row0 = blockIdx.y * 128, col0 = blockIdx.x * 128;
  const int wm = (w & 1) * 64, wn = (w >> 1) * 64;

  f32x4 acc[4][4] = {};

  for (int k0 = 0; k0 < K; k0 += BK) {
    __syncthreads();
#pragma unroll
    for (int i = 0; i < 2; ++i) {
      int c = i * 256 + w * 64 + lane;          // 16B chunk id, 4 chunks/row
      int r = c >> 2, ko = (c & 3) * 8;
      gload16(A + (size_t)(row0 + r) * K + k0 + ko,
              (char*)As + (i * 256 + w * 64) * 16);
      gload16(W + (size_t)(col0 + r) * K + k0 + ko,
              (char*)Ws + (i * 256 + w * 64) * 16);
    }
    __syncthreads();

    bf16x8 af[4], bfr[4];
#pragma unroll
    for (int mt = 0; mt < 4; ++mt)
      af[mt] = *(const bf16x8*)((char*)As + (wm + mt * 16 + l16) * 64 + quad * 16);
#pragma unroll
    for (int nt = 0; nt < 4; ++nt)
      bfr[nt] = *(const bf16x8*)((char*)Ws + (wn + nt * 16 + l16) * 64 + quad * 16);
#pragma unroll
    for (int mt = 0; mt < 4; ++mt)
#pragma unroll
      for (int nt = 0; nt < 4; ++nt)
        acc[mt][nt] = MFMA16(af[mt], bfr[nt], acc[mt][nt]);
  }

#pragma unroll
  for (int mt = 0; mt < 4; ++mt)
#pragma unroll
    for (int nt = 0; nt < 4; ++nt)
#pragma unroll
      for (int r = 0; r < 4; ++r) {
        int row = row0 + wm + mt * 16 + quad * 4 + r;
        int col = col0 + wn + nt * 16 + l16;
        float v = acc[mt][nt][r];
        if (OUT_MODE == 0)
          ((ushort_t*)Cv)[(size_t)row * N + col] = f2bf(v);
        else if (OUT_MODE == 1)
          ((float*)Cv)[(size_t)row * N + col] = v;
        else
          ((ushort_t*)Cv)[(size_t)col * M + row] = f2bf(v);  // C^T
      }
}

// ---------------------------------------------------------------------------
// 256x256-tile 4-phase GEMM (T2+T3/T4+T5), unchanged from round 4 (matched).
// ---------------------------------------------------------------------------
__device__ __forceinline__ void stage_half(const ushort_t* __restrict__ src,
                                           int rowBase, int k0, char* ldsHalf,
                                           int wid, int lane, int K) {
#pragma unroll
  for (int j = 0; j < 2; ++j) {
    int ct = wid * 64 + j * 512 + lane;     // chunk 0..1023 of 16B
    int r = ct >> 3, c = ct & 7;
    gload16(src + (size_t)(rowBase + r) * K + k0 + ((c ^ (r & 7)) << 3),
            ldsHalf + (wid * 64 + j * 512) * 16);
  }
}

__device__ __forceinline__ bf16x8 readfrag(const char* base, int row, int cc) {
  return *(const bf16x8*)(base + row * 128 + ((cc ^ (row & 7)) << 4));
}

template <int OUT_MODE>
__global__ __launch_bounds__(512, 2) void gemm256(
    const ushort_t* __restrict__ A, const ushort_t* __restrict__ W,
    void* __restrict__ Cv, int M, int N, int K) {
  __shared__ __align__(16) char lds[131072];
  const int tid = threadIdx.x, lane = tid & 63, wid = tid >> 6;
  const int quad = lane >> 4, l16 = lane & 15;
  const int wr = wid >> 2, wc = wid & 3;
  const int row0 = blockIdx.y * 256, col0 = blockIdx.x * 256;
  const int KT = K >> 6;

  f32x4 acc[8][4] = {};

  stage_half(A, row0,       0, lds,                 wid, lane, K);
  stage_half(A, row0 + 128, 0, lds + 16384,         wid, lane, K);
  stage_half(W, col0,       0, lds + 65536,         wid, lane, K);
  stage_half(W, col0 + 128, 0, lds + 65536 + 16384, wid, lane, K);
  asm volatile("s_waitcnt vmcnt(0)" ::: "memory");
  __builtin_amdgcn_s_barrier();

  for (int u = 0; u < KT; ++u) {
    char* bA = lds + (u & 1) * 32768;
    char* bB = lds + 65536 + (u & 1) * 32768;
    char* nA = lds + ((u + 1) & 1) * 32768;
    char* nB = lds + 65536 + ((u + 1) & 1) * 32768;
    const bool st = (u + 1 < KT);
    const int kn = (u + 1) << 6;

    bf16x8 bfrag[4][2];
#pragma unroll
    for (int ph = 0; ph < 4; ++ph) {
      bf16x8 afr[2][2];
#pragma unroll
      for (int mi = 0; mi < 2; ++mi)
#pragma unroll
        for (int kc = 0; kc < 2; ++kc)
          afr[mi][kc] =
              readfrag(bA, wr * 128 + (ph * 2 + mi) * 16 + l16, kc * 4 + quad);
      if (ph == 0) {
#pragma unroll
        for (int nt = 0; nt < 4; ++nt)
#pragma unroll
          for (int kc = 0; kc < 2; ++kc)
            bfrag[nt][kc] = readfrag(bB, wc * 64 + nt * 16 + l16, kc * 4 + quad);
        if (st) {
          stage_half(A, row0,       kn, nA,         wid, lane, K);
          stage_half(A, row0 + 128, kn, nA + 16384, wid, lane, K);
        }
      }
      if (ph == 1 && st) {
        stage_half(W, col0,       kn, nB,         wid, lane, K);
        stage_half(W, col0 + 128, kn, nB + 16384, wid, lane, K);
      }

      __builtin_amdgcn_s_barrier();
      asm volatile("s_waitcnt lgkmcnt(0)" ::: "memory");
      __builtin_amdgcn_sched_barrier(0);
      __builtin_amdgcn_s_setprio(1);
#pragma unroll
      for (int mi = 0; mi < 2; ++mi)
#pragma unroll
        for (int nt = 0; nt < 4; ++nt)
#pragma unroll
          for (int kc = 0; kc < 2; ++kc)
            acc[ph * 2 + mi][nt] =
                MFMA16(afr[mi][kc], bfrag[nt][kc], acc[ph * 2 + mi][nt]);
      __builtin_amdgcn_s_setprio(0);
      if (ph == 3)
        asm volatile("s_waitcnt vmcnt(0)" ::: "memory");
      __builtin_amdgcn_s_barrier();
    }
  }

#pragma unroll
  for (int mt = 0; mt < 8; ++mt)
#pragma unroll
    for (int nt = 0; nt < 4; ++nt)
#pragma unroll
      for (int r = 0; r < 4; ++r) {
        int row = row0 + wr * 128 + mt * 16 + quad * 4 + r;
        int col = col0 + wc * 64 + nt * 16 + l16;
        float v = acc[mt][nt][r];
        if (OUT_MODE == 0)
          ((ushort_t*)Cv)[(size_t)row * N + col] = f2bf(v);
        else
          ((float*)Cv)[(size_t)row * N + col] = v;
      }
}

// ---------------------------------------------------------------------------
// RoPE in place on bf16 q and k (unchanged)
// ---------------------------------------------------------------------------
__global__ void rope_bf16(ushort_t* __restrict__ q, ushort_t* __restrict__ k,
                          const float* __restrict__ cs,
                          const float* __restrict__ sn) {
  int idx = blockIdx.x * 256 + threadIdx.x;
  int jg = (idx & 15) * 4;
  int t = idx >> 4;
  int hh = t % (NH_ + NKV_);
  int bs = t / (NH_ + NKV_);
  int s = bs & (S_ - 1);
  float4 c4 = *(const float4*)(cs + s * 64 + jg);
  float4 s4 = *(const float4*)(sn + s * 64 + jg);
  ushort_t* p = (hh < NH_)
      ? q + (size_t)bs * QDIM + hh * HD_ + 2 * jg
      : k + (size_t)bs * KVDIM + (hh - NH_) * HD_ + 2 * jg;
  bf16x8 v = *(const bf16x8*)p;
  float cc[4] = {c4.x, c4.y, c4.z, c4.w};
  float ss[4] = {s4.x, s4.y, s4.z, s4.w};
  bf16x8 o;
#pragma unroll
  for (int u = 0; u < 4; ++u) {
    float xr = bf2f((ushort_t)v[2 * u]);
    float xi = bf2f((ushort_t)v[2 * u + 1]);
    o[2 * u]     = (short)f2bf(xr * cc[u] - xi * ss[u]);
    o[2 * u + 1] = (short)f2bf(xr * ss[u] + xi * cc[u]);
  }
  *(bf16x8*)p = o;
}

// ---------------------------------------------------------------------------
// MFMA flash attention v5: single-buffered K/V (LDS 41984 -> 3 blocks/CU,
// 12 waves/CU) + causal pairing + DPP softmax reductions (VALU pipe instead
// of LDS-pipe shuffles). Structure per kv-iter: {barrier; stage K,V;
// barrier(drain); QK^T; softmax(DPP); P->LDS; PV}. Q staged per half into
// the K buffer (wave-own rows; lgkmcnt(0) orders qf reads vs K staging).
// ---------------------------------------------------------------------------
__global__ __launch_bounds__(256, 3) void attn_mfma(
    const ushort_t* __restrict__ qb, const ushort_t* __restrict__ kb,
    const ushort_t* __restrict__ vt, ushort_t* __restrict__ ob) {
  __shared__ __align__(16) char smem[16384 + 16384 + 4 * 2304];  // 41984 B
  char* Ks = smem;                    // 64 rows x 256B (swizzled); Q staging
  char* Vs = smem + 16384;            // 128 rows x 128B (swizzled V^T)
  const int tid = threadIdx.x, lane = tid & 63, w = tid >> 6;
  const int quad = lane >> 4, l16 = lane & 15;
  char* psw = smem + 32768 + w * 2304;   // per-wave P: 16 rows x 144B
  const int h = blockIdx.y, b = blockIdx.z;
  const int kvh = h >> 2;
  const float C = 0.12756113f;        // (1/sqrt(128)) * log2(e)

  for (int half = 0; half < 2; ++half) {
    const int qt = (half == 0) ? (S_ / 64 - 1) - blockIdx.x : blockIdx.x;
    const int q0 = qt * 64;

    __syncthreads();   // prior half's K/V reads done before Q re-stage
    // ---- stage Q[64][128] into Ks (swizzled), wave-own rows ----
#pragma unroll
    for (int i = 0; i < 4; ++i) {
      int r0 = w * 16 + i * 4;
      int r = r0 + (lane >> 4);
      int c = (lane & 15) ^ (r & 15);
      gload16(qb + (size_t)(b * S_ + q0 + r) * QDIM + h * HD_ + c * 8,
              Ks + r0 * 256);
    }
    __syncthreads();
    bf16x8 qf[4];
#pragma unroll
    for (int t = 0; t < 4; ++t)
      qf[t] = *(const bf16x8*)(Ks + (w * 16 + l16) * 256 +
                               (((t * 4 + quad) ^ l16) * 16));
    // qf (wave-own rows) must land before this wave's K-stage overwrites them
    asm volatile("s_waitcnt lgkmcnt(0)" ::: "memory");

    float m_[4], l_[4];
    f32x4 o_[8] = {};
#pragma unroll
    for (int r = 0; r < 4; ++r) { m_[r] = -1e30f; l_[r] = 0.f; }

    for (int kt = 0; kt <= qt; ++kt) {
      __syncthreads();                  // prior iteration's K/V reads done
      // ---- stage K[64][128] and V^T[128][64] (swizzled) ----
#pragma unroll
      for (int i = 0; i < 4; ++i) {
        int r0 = w * 16 + i * 4;
        int r = r0 + (lane >> 4);
        int c = (lane & 15) ^ (r & 15);
        gload16(kb + (size_t)(b * S_ + kt * 64 + r) * KVDIM + kvh * HD_ + c * 8,
                Ks + r0 * 256);
        int vr0 = w * 32 + i * 8;
        int vr = vr0 + (lane >> 3);
        int vc = (lane & 7) ^ (vr & 7);
        gload16(vt + (size_t)(kvh * HD_ + vr) * MROWS + b * S_ + kt * 64 + vc * 8,
                Vs + vr0 * 128);
      }
      __syncthreads();                  // drain: K/V visible to all waves

      // ---- S = Q K^T : 4 kv tiles of 16 (skip fully-masked tiles on diag) --
      const int ntmax = (kt == qt) ? w : 3;
      f32x4 s[4];
      __builtin_amdgcn_s_setprio(1);
#pragma unroll
      for (int nt = 0; nt < 4; ++nt) {
        if (nt <= ntmax) {
          f32x4 a = {0.f, 0.f, 0.f, 0.f};
#pragma unroll
          for (int t = 0; t < 4; ++t) {
            bf16x8 kf = *(const bf16x8*)(Ks + (nt * 16 + l16) * 256 +
                                         (((t * 4 + quad) ^ l16) * 16));
            a = MFMA16(qf[t], kf, a);
          }
          s[nt] = a;
        } else {
          s[nt] = (f32x4){-INFINITY, -INFINITY, -INFINITY, -INFINITY};
        }
      }
      __builtin_amdgcn_s_setprio(0);

      // ---- online softmax: DPP 16-lane reduces (VALU pipe, no LDS) ----
      float p[4][4], al[4];
#pragma unroll
      for (int r = 0; r < 4; ++r) {
        float v[4];
#pragma unroll
        for (int nt = 0; nt < 4; ++nt) {
          float vv = s[nt][r] * C;
          if (kt == qt && nt == w && l16 > quad * 4 + r) vv = -INFINITY;
          v[nt] = vv;
        }
        float mx = fmaxf(fmaxf(v[0], v[1]), fmaxf(v[2], v[3]));
        mx = dpp_max16(mx);
        float mnew = fmaxf(m_[r], mx);
        float a0 = __builtin_amdgcn_exp2f(m_[r] - mnew);
        float sum = 0.f;
#pragma unroll
        for (int nt = 0; nt < 4; ++nt) {
          p[nt][r] = __builtin_amdgcn_exp2f(v[nt] - mnew);
          sum += p[nt][r];
        }
        sum = dpp_sum16(sum);
        l_[r] = l_[r] * a0 + sum;
        m_[r] = mnew;
        al[r] = a0;
      }

      // ---- P -> per-wave LDS first (lgkm wait overlaps the O-rescale) ----
#pragma unroll
      for (int r = 0; r < 4; ++r)
#pragma unroll
        for (int nt = 0; nt < 4; ++nt)
          ((ushort_t*)psw)[(quad * 4 + r) * 72 + nt * 16 + l16] = f2bf(p[nt][r]);

#pragma unroll
      for (int dt = 0; dt < 8; ++dt)
#pragma unroll
        for (int r = 0; r < 4; ++r) o_[dt][r] *= al[r];

      asm volatile("s_waitcnt lgkmcnt(0)" ::: "memory");
      bf16x8 pf[2];
#pragma unroll
      for (int kc = 0; kc < 2; ++kc)
        pf[kc] = *(const bf16x8*)(psw + l16 * 144 + kc * 64 + quad * 16);

      // ---- O += P V : 8 d-tiles x 2 k-chunks ----
      __builtin_amdgcn_s_setprio(1);
#pragma unroll
      for (int dt = 0; dt < 8; ++dt) {
#pragma unroll
        for (int kc = 0; kc < 2; ++kc) {
          bf16x8 vf = *(const bf16x8*)(Vs + (dt * 16 + l16) * 128 +
                                       (((kc * 4 + quad) ^ (l16 & 7)) * 16));
          o_[dt] = MFMA16(pf[kc], vf, o_[dt]);
        }
      }
      __builtin_amdgcn_s_setprio(0);
    }

    // ---- epilogue: normalize, store bf16 (b,s,h,d) ----
#pragma unroll
    for (int r = 0; r < 4; ++r) {
      float linv = 1.0f / l_[r];
      size_t base = (size_t)(b * S_ + q0 + w * 16 + quad * 4 + r) * QDIM + h * HD_;
#pragma unroll
      for (int dt = 0; dt < 8; ++dt)
        ob[base + dt * 16 + l16] = f2bf(o_[dt][r] * linv);
    }
  }
}

// ---------------------------------------------------------------------------
// Launch. Workspace layout (MiB offsets), 160 MiB total:
//   0: xb(32, reused for wob) | 32: wqb(32) | 64: wkb(8) | 72: wvb(8)
//  80: qbuf(32) | 112: kbuf(8) | 120: vtb(8) | 128: attnb(32)
// ---------------------------------------------------------------------------
extern "C" void kernel_launch(void* const* d_in, const int* in_sizes, int n_in,
                              void* d_out, int out_size, void* d_ws, size_t ws_size,
                              hipStream_t stream) {
  const float* x  = (const float*)d_in[0];
  const float* wq = (const float*)d_in[1];
  const float* wk = (const float*)d_in[2];
  const float* wv = (const float*)d_in[3];
  const float* wo = (const float*)d_in[4];
  const float* fc = (const float*)d_in[5];
  const float* fs = (const float*)d_in[6];
  float* out = (float*)d_out;

  char* ws = (char*)d_ws;
  ushort_t* xb    = (ushort_t*)(ws);
  ushort_t* wqb   = (ushort_t*)(ws + (32ull << 20));
  ushort_t* wkb   = (ushort_t*)(ws + (64ull << 20));
  ushort_t* wvb   = (ushort_t*)(ws + (72ull << 20));
  ushort_t* qbuf  = (ushort_t*)(ws + (80ull << 20));
  ushort_t* kbuf  = (ushort_t*)(ws + (112ull << 20));
  ushort_t* vtb   = (ushort_t*)(ws + (120ull << 20));
  ushort_t* attnb = (ushort_t*)(ws + (128ull << 20));
  ushort_t* wob   = xb;  // x dead after projections

  dim3 blk(256);
  dim3 blk512(512);

  conv_f32_bf16<<<(MROWS * DIM_) / 2048, blk, 0, stream>>>(x, xb);
  conv_f32_bf16<<<(QDIM * DIM_) / 2048, blk, 0, stream>>>(wq, wqb);
  conv_f32_bf16<<<(KVDIM * DIM_) / 2048, blk, 0, stream>>>(wk, wkb);
  conv_f32_bf16<<<(KVDIM * DIM_) / 2048, blk, 0, stream>>>(wv, wvb);

  gemm256<0><<<dim3(QDIM / 256, MROWS / 256), blk512, 0, stream>>>(xb, wqb, qbuf, MROWS, QDIM, DIM_);
  gemm_bf16<0><<<dim3(KVDIM / 128, MROWS / 128), blk, 0, stream>>>(xb, wkb, kbuf, MROWS, KVDIM, DIM_);
  gemm_bf16<2><<<dim3(KVDIM / 128, MROWS / 128), blk, 0, stream>>>(xb, wvb, vtb, MROWS, KVDIM, DIM_);

  rope_bf16<<<(MROWS * (NH_ + NKV_) * 16) / 256, blk, 0, stream>>>(qbuf, kbuf, fc, fs);

  // Paired causal tiles: grid.x = 16, each block does qt = 31-x and qt = x.
  attn_mfma<<<dim3(S_ / 128, NH_, B_), blk, 0, stream>>>(qbuf, kbuf, vtb, attnb);

  conv_f32_bf16<<<(QDIM * DIM_) / 2048, blk, 0, stream>>>(wo, wob);
  gemm256<1><<<dim3(QDIM / 256, MROWS / 256), blk512, 0, stream>>>(attnb, wob, out, MROWS, QDIM, DIM_);
}